// Round 9
// baseline (357.313 us; speedup 1.0000x reference)
//
#include <hip/hip_runtime.h>
#include <hip/hip_fp16.h>
#include <cmath>

// Fixed problem shape: x = (8, 3, 1024, 1024) fp32.
#define HH   1024
#define WW   1024
#define HW   (HH * WW)

#define SW    64      // tile width  (output cols per block)
#define TH    64      // tile height (output rows per block)
#define T31R  94      // TH + 30
#define T7R   70      // TH + 6
#define NIT   6       // phase-1 iterations (6*16 = 96 >= 94 staged rows)
#define SPX   96      // stage row width in px (64 + 16 left + 16 right halo)
#define SOFF  16      // stage col s  <->  image col x0 - SOFF + s
#define UPR   24      // float4 units per stage row (24*4 = 96)

// ---- compile-time gaussian weights (matches np: exp(-d^2/(2 sigma^2)) / sum) ----
constexpr double cexp(double v) {
    double term = 1.0, sum = 1.0;
    for (int i = 1; i < 64; ++i) { term *= v / (double)i; sum += term; }
    return sum;
}
struct GW { float g31[31]; float g7[7]; };
constexpr GW make_gw() {
    GW r{};
    double t31[31]; double s31 = 0.0;
    for (int i = 0; i < 31; ++i) { double d = (double)(i - 15); t31[i] = cexp(-d * d / 128.0); s31 += t31[i]; }
    for (int i = 0; i < 31; ++i) r.g31[i] = (float)(t31[i] / s31);
    double t7[7]; double s7 = 0.0;
    for (int i = 0; i < 7; ++i) { double d = (double)(i - 3); t7[i] = cexp(-d * d / 4.5); s7 += t7[i]; }
    for (int i = 0; i < 7; ++i) r.g7[i] = (float)(t7[i] / s7);
    return r;
}
__constant__ GW GWC = make_gw();

// ---------------------------------------------------------------------------
// V9 vs V8/V7 (V8 producer/consumer REGRESSED 82-90µs -> revert structure;
// V7 75µs with all pipes <=37%: wall ~= SUM of pipe work, schedule changes
// exhausted -> reduce the WORK):
//  1. Phase 2 register-blocked: each thread owns 4 rows x 4 cols; taps read
//     ONCE (34 b128 + 10 b64 per thread) and scatter-accumulated into 4
//     row-accumulators. LDS reads 152 -> 44 per thread (3.5x less traffic),
//     same FMA count. All indices compile-time (full unroll).
//  2. Luma stage in fp32: h-blur reads ds_read_b128, ZERO cvt ops in the
//     31-tap loops (V7 still had 18 cvt/unit in phase 1).
// Structure = V7: barrier-free phase 1 (per-wave private stage rows),
// sched_barrier-pinned register prefetch, ONE __syncthreads, 256 thr.
// LDS = 24064 (t31 fp32) + 8960 (t7 fp16) + 6144 (stage fp32) = 39168 B
// -> 4 blocks/CU, 16 waves/CU; grid 2048 = 2 rounds.
// ---------------------------------------------------------------------------
__global__ __launch_bounds__(256, 4)
void fused_tile(const float* __restrict__ x,
                const float* __restrict__ clar,
                const float* __restrict__ tex,
                float* __restrict__ out) {
    __shared__ __align__(16) float  t31s [T31R][SW];      // 24064 B fp32
    __shared__ __align__(16) __half t7s  [T7R][SW];       //  8960 B fp16
    __shared__ __align__(16) float  stage[4][4][SPX];     //  6144 B fp32

    // XCD swizzle: vertically-adjacent bands of one (img,strip) column land
    // on one XCD so the 30-row halo overlap reuses L2.
    const int id    = blockIdx.x;
    const int xcd   = id & 7;
    const int j8    = id >> 3;             // 0..255
    const int combo = j8 & 127;            // img*16 + strip
    const int sub   = j8 >> 7;             // 0..1
    const int band  = xcd * 2 + sub;       // 0..15
    const int img   = combo >> 4;
    const int strip = combo & 15;

    const int y0 = band * TH;
    const int x0 = strip * SW;
    const int t  = threadIdx.x;
    const int w    = t >> 6;               // wave 0..3
    const int lane = t & 63;

    const float* xb = x   + (size_t)img * 3 * HW;
    float*       ob = out + (size_t)img * 3 * HW;

    // ---- per-wave staging geometry: 4 rows x 24 units = 96 units over 64
    // lanes. unit0 = lane; unit1 = lane+64 (clamped duplicates -> branch-free) ----
    const int r0s = lane / UPR;                 // 0..2
    const int c0s = lane - UPR * r0s;
    const int u1  = lane + 64;                  // 64..127
    const int r1r = u1 / UPR;                   // 2..5
    const int r1s = r1r > 3 ? 3 : r1r;          // clamp -> duplicate slots
    const int c1s = u1 - UPR * r1r;             // 0..23
    const int col0 = x0 - SOFF + 4 * c0s;
    const int col1 = x0 - SOFF + 4 * c1s;
    const int col0c = col0 < 0 ? 0 : (col0 > WW - 4 ? WW - 4 : col0);
    const int col1c = col1 < 0 ? 0 : (col1 > WW - 4 ? WW - 4 : col1);
    const float cm0 = ((unsigned)col0 < (unsigned)WW) ? 1.f : 0.f;
    const float cm1 = ((unsigned)col1 < (unsigned)WW) ? 1.f : 0.f;

    float4 R0, G0, B0, R1, G1, B1;
    float  mk0, mk1;

    // issue iteration `it`'s global loads into registers — UNCONDITIONAL
    // (clamped addresses), masks applied at consume time.
    auto issue = [&](int it) {
        const int gbase = it * 16;
        {
            const int tr = gbase + 4 * w + r0s;
            const int y  = y0 - 15 + tr;
            const int yc = y < 0 ? 0 : (y > HH - 1 ? HH - 1 : y);
            mk0 = (tr < T31R && (unsigned)y < (unsigned)HH) ? cm0 : 0.f;
            const float* xr = xb + (size_t)yc * WW + col0c;
            R0 = *(const float4*)(xr);
            G0 = *(const float4*)(xr + HW);
            B0 = *(const float4*)(xr + 2 * HW);
        }
        {
            const int tr = gbase + 4 * w + r1s;
            const int y  = y0 - 15 + tr;
            const int yc = y < 0 ? 0 : (y > HH - 1 ? HH - 1 : y);
            mk1 = (tr < T31R && (unsigned)y < (unsigned)HH) ? cm1 : 0.f;
            const float* xr = xb + (size_t)yc * WW + col1c;
            R1 = *(const float4*)(xr);
            G1 = *(const float4*)(xr + HW);
            B1 = *(const float4*)(xr + 2 * HW);
        }
    };

    issue(0);   // prologue
    __builtin_amdgcn_sched_barrier(0);

    // -------- phase 1: barrier-free; wave w stages and h-blurs its own
    // rows tr = 16*it + 4w + r. --------
    for (int it = 0; it < NIT; ++it) {
        // consume prefetched regs -> masked fp32 luma into this wave's stage
        {
            float4 L0;
            L0.x = mk0 * fmaf(0.2126f, R0.x, fmaf(0.7152f, G0.x, 0.0722f * B0.x));
            L0.y = mk0 * fmaf(0.2126f, R0.y, fmaf(0.7152f, G0.y, 0.0722f * B0.y));
            L0.z = mk0 * fmaf(0.2126f, R0.z, fmaf(0.7152f, G0.z, 0.0722f * B0.z));
            L0.w = mk0 * fmaf(0.2126f, R0.w, fmaf(0.7152f, G0.w, 0.0722f * B0.w));
            *(float4*)&stage[w][r0s][4 * c0s] = L0;      // b128, 16B aligned
            float4 L1;
            L1.x = mk1 * fmaf(0.2126f, R1.x, fmaf(0.7152f, G1.x, 0.0722f * B1.x));
            L1.y = mk1 * fmaf(0.2126f, R1.y, fmaf(0.7152f, G1.y, 0.0722f * B1.y));
            L1.z = mk1 * fmaf(0.2126f, R1.z, fmaf(0.7152f, G1.z, 0.0722f * B1.z));
            L1.w = mk1 * fmaf(0.2126f, R1.w, fmaf(0.7152f, G1.w, 0.0722f * B1.w));
            *(float4*)&stage[w][r1s][4 * c1s] = L1;
        }

        // issue next iteration's loads; fence pins them above the h-blur
        if (it + 1 < NIT) issue(it + 1);
        __builtin_amdgcn_sched_barrier(0);

        // h-blur: thread -> stage row (t>>4)&3 of its own wave, 4 px at 4*(t&15)
        {
            const int lr = (t >> 4) & 3;
            const int c  = t & 15;
            const int tr = it * 16 + (t >> 4);
            if (tr < T31R) {
                float win[36];
                #pragma unroll
                for (int q = 0; q < 9; ++q) {
                    const float4 u = *(const float4*)&stage[w][lr][4 * c + 4 * q]; // b128
                    win[4 * q]     = u.x; win[4 * q + 1] = u.y;
                    win[4 * q + 2] = u.z; win[4 * q + 3] = u.w;
                }
                float o[4] = {0.f, 0.f, 0.f, 0.f};
                float p[4] = {0.f, 0.f, 0.f, 0.f};
                #pragma unroll
                for (int s = 0; s < 31; ++s) {
                    const float g = GWC.g31[s];
                    o[0] = fmaf(g, win[1 + s], o[0]);
                    o[1] = fmaf(g, win[2 + s], o[1]);
                    o[2] = fmaf(g, win[3 + s], o[2]);
                    o[3] = fmaf(g, win[4 + s], o[3]);
                }
                #pragma unroll
                for (int s = 0; s < 7; ++s) {
                    const float g = GWC.g7[s];
                    p[0] = fmaf(g, win[13 + s], p[0]);
                    p[1] = fmaf(g, win[14 + s], p[1]);
                    p[2] = fmaf(g, win[15 + s], p[2]);
                    p[3] = fmaf(g, win[16 + s], p[3]);
                }
                *(float4*)&t31s[tr][4 * c] = make_float4(o[0], o[1], o[2], o[3]);
                if (tr >= 12 && tr < 12 + T7R) {
                    union { float2 f; __half2 h[2]; } V;
                    V.h[0] = __floats2half2_rn(p[0], p[1]);
                    V.h[1] = __floats2half2_rn(p[2], p[3]);
                    *(float2*)&t7s[tr - 12][4 * c] = V.f;
                }
            }
        }
        // NO __syncthreads here
    }

    __syncthreads();   // the ONLY barrier: t31s/t7s complete before phase 2

    // -------- phase 2: register-blocked vertical conv. Thread owns a
    // 4-row x 4-col output tile; each tap row read ONCE (b128) and
    // scatter-accumulated into 4 accumulators. --------
    const float ca = tanhf(clar[0]) * 0.5f;
    const float ta = tanhf(tex[0]) * 0.3f;

    const int rg = t >> 4;            // row group 0..15
    const int r0 = rg * 4;            // output rows r0..r0+3 (tile-rel)
    const int cc = 4 * (t & 15);      // col within tile, float4-aligned

    float4 a31[4];
    float4 a7[4];
    #pragma unroll
    for (int j = 0; j < 4; ++j) {
        a31[j] = make_float4(0.f, 0.f, 0.f, 0.f);
        a7[j]  = make_float4(0.f, 0.f, 0.f, 0.f);
    }

    // 34 tap rows, each read once; contributes g31[q-j] to output j.
    #pragma unroll
    for (int q = 0; q < 34; ++q) {
        const float4 tap = *(const float4*)&t31s[r0 + q][cc];   // ds_read_b128
        #pragma unroll
        for (int j = 0; j < 4; ++j) {
            const int s = q - j;
            if (s >= 0 && s <= 30) {            // compile-time after unroll
                const float g = GWC.g31[s];
                a31[j].x = fmaf(g, tap.x, a31[j].x);
                a31[j].y = fmaf(g, tap.y, a31[j].y);
                a31[j].z = fmaf(g, tap.z, a31[j].z);
                a31[j].w = fmaf(g, tap.w, a31[j].w);
            }
        }
    }
    // 10 t7 tap rows (fp16), each read once.
    #pragma unroll
    for (int q = 0; q < 10; ++q) {
        union { float2 f; __half2 h[2]; } U;
        U.f = *(const float2*)&t7s[r0 + q][cc];                 // ds_read_b64
        const float2 a = __half22float2(U.h[0]);
        const float2 b = __half22float2(U.h[1]);
        #pragma unroll
        for (int j = 0; j < 4; ++j) {
            const int s = q - j;
            if (s >= 0 && s <= 6) {
                const float g = GWC.g7[s];
                a7[j].x = fmaf(g, a.x, a7[j].x);
                a7[j].y = fmaf(g, a.y, a7[j].y);
                a7[j].z = fmaf(g, b.x, a7[j].z);
                a7[j].w = fmaf(g, b.y, a7[j].w);
            }
        }
    }

    // combine + store, one row at a time (x re-read is L2/L3-hot)
    #pragma unroll
    for (int j = 0; j < 4; ++j) {
        const int y = y0 + r0 + j;
        const float* px = xb + (size_t)y * WW + x0 + cc;
        const float4 R  = *(const float4*)(px);
        const float4 G  = *(const float4*)(px + HW);
        const float4 Bc = *(const float4*)(px + 2 * HW);

        const float L0 = fmaf(0.2126f, R.x, fmaf(0.7152f, G.x, 0.0722f * Bc.x));
        const float L1 = fmaf(0.2126f, R.y, fmaf(0.7152f, G.y, 0.0722f * Bc.y));
        const float L2 = fmaf(0.2126f, R.z, fmaf(0.7152f, G.z, 0.0722f * Bc.z));
        const float L3 = fmaf(0.2126f, R.w, fmaf(0.7152f, G.w, 0.0722f * Bc.w));
        const float e0 = L0 + ca * (L0 - a31[j].x) + ta * (L0 - a7[j].x);
        const float e1 = L1 + ca * (L1 - a31[j].y) + ta * (L1 - a7[j].y);
        const float e2 = L2 + ca * (L2 - a31[j].z) + ta * (L2 - a7[j].z);
        const float e3 = L3 + ca * (L3 - a31[j].w) + ta * (L3 - a7[j].w);
        // v_rcp_f32 approx: rel err ~1ulp, far below the 3.9e-3 tolerance
        const float r0r = (e0 + 1e-6f) * __builtin_amdgcn_rcpf(L0 + 1e-6f);
        const float r1r = (e1 + 1e-6f) * __builtin_amdgcn_rcpf(L1 + 1e-6f);
        const float r2r = (e2 + 1e-6f) * __builtin_amdgcn_rcpf(L2 + 1e-6f);
        const float r3r = (e3 + 1e-6f) * __builtin_amdgcn_rcpf(L3 + 1e-6f);

        float4 o0, o1, o2;
        o0.x = fminf(fmaxf(R.x  * r0r, 0.f), 1.f);
        o0.y = fminf(fmaxf(R.y  * r1r, 0.f), 1.f);
        o0.z = fminf(fmaxf(R.z  * r2r, 0.f), 1.f);
        o0.w = fminf(fmaxf(R.w  * r3r, 0.f), 1.f);
        o1.x = fminf(fmaxf(G.x  * r0r, 0.f), 1.f);
        o1.y = fminf(fmaxf(G.y  * r1r, 0.f), 1.f);
        o1.z = fminf(fmaxf(G.z  * r2r, 0.f), 1.f);
        o1.w = fminf(fmaxf(G.w  * r3r, 0.f), 1.f);
        o2.x = fminf(fmaxf(Bc.x * r0r, 0.f), 1.f);
        o2.y = fminf(fmaxf(Bc.y * r1r, 0.f), 1.f);
        o2.z = fminf(fmaxf(Bc.z * r2r, 0.f), 1.f);
        o2.w = fminf(fmaxf(Bc.w * r3r, 0.f), 1.f);

        float* qo = ob + (size_t)y * WW + x0 + cc;
        *(float4*)(qo)          = o0;
        *(float4*)(qo + HW)     = o1;
        *(float4*)(qo + 2 * HW) = o2;
    }
}

extern "C" void kernel_launch(void* const* d_in, const int* in_sizes, int n_in,
                              void* d_out, int out_size, void* d_ws, size_t ws_size,
                              hipStream_t stream) {
    const float* x    = (const float*)d_in[0];
    const float* clar = (const float*)d_in[1];
    const float* tex  = (const float*)d_in[2];
    float* out = (float*)d_out;

    dim3 grid(8 * 16 * 16);  // 2048 blocks: 8 imgs x 16 strips x 16 bands; 4/CU x 2 rounds
    dim3 block(256);
    hipLaunchKernelGGL(fused_tile, grid, block, 0, stream, x, clar, tex, out);
}

// Round 10
// 308.554 us; speedup vs baseline: 1.1580x; 1.1580x over previous
//
#include <hip/hip_runtime.h>
#include <hip/hip_fp16.h>
#include <cmath>

// Fixed problem shape: x = (8, 3, 1024, 1024) fp32.
#define HH   1024
#define WW   1024
#define HW   (HH * WW)

#define SW    64      // tile width  (output cols per block)
#define TH    64      // tile height (output rows per block)
#define T31R  94      // TH + 30
#define T7R   70      // TH + 6
#define NIT   3       // phase-1 iterations (3*32 = 96 >= 94 staged rows)
#define SPX   96      // stage row width in px (64 + 16 left + 16 right halo)
#define SOFF  16      // stage col s  <->  image col x0 - SOFF + s
#define UPR   24      // float4 units per stage row (24*4 = 96)

// ---- compile-time gaussian weights (matches np: exp(-d^2/(2 sigma^2)) / sum) ----
constexpr double cexp(double v) {
    double term = 1.0, sum = 1.0;
    for (int i = 1; i < 64; ++i) { term *= v / (double)i; sum += term; }
    return sum;
}
struct GW { float g31[31]; float g7[7]; };
constexpr GW make_gw() {
    GW r{};
    double t31[31]; double s31 = 0.0;
    for (int i = 0; i < 31; ++i) { double d = (double)(i - 15); t31[i] = cexp(-d * d / 128.0); s31 += t31[i]; }
    for (int i = 0; i < 31; ++i) r.g31[i] = (float)(t31[i] / s31);
    double t7[7]; double s7 = 0.0;
    for (int i = 0; i < 7; ++i) { double d = (double)(i - 3); t7[i] = cexp(-d * d / 4.5); s7 += t7[i]; }
    for (int i = 0; i < 7; ++i) r.g7[i] = (float)(t7[i] / s7);
    return r;
}
__constant__ GW GWC = make_gw();

// ---------------------------------------------------------------------------
// V10 vs V9 (247µs DISASTER: 34-deep unrolled scatter -> scratch spills,
// +280MB r/w scratch traffic; revert) and V7 (best, 75µs):
// V10 = V7 VERBATIM except phase 2 shares each tap between this thread's
// 2 output rows: read tap rows q=0..31 ONCE (b128), accumulate into A0
// (weight g31[q]) and A1 (weight g31[q-1]). LDS reads/thread 76 -> 41;
// accumulator cost only +16 VGPR; loop shape (32 iters x ~9 ops) matches
// what the compiler scheduled cleanly in V7 (no V9-style pyramid).
// x re-reads for both rows are issued BEFORE the conv (fence-pinned) so
// global latency hides under the 31-tap chains.
// Theory: phase 2 is LDS-pipe serialized (~24µs/CU of ds_read time at 76
// reads); halving reads should cut wall 75 -> ~63-67. V9's 3.22 TB/s
// dispatch proved memory BW headroom exists; serialization is on-chip.
// LDS = 24064 (t31 fp32) + 8960 (t7 fp16) + 6144 (stage fp16) = 39168 B
// -> 4 blocks/CU at 512 thr = 32 waves/CU. Grid 2048 = 2 rounds.
// ---------------------------------------------------------------------------
__global__ __launch_bounds__(512, 4)
void fused_tile(const float* __restrict__ x,
                const float* __restrict__ clar,
                const float* __restrict__ tex,
                float* __restrict__ out) {
    __shared__ __align__(16) float  t31s [T31R][SW];      // 24064 B fp32
    __shared__ __align__(16) __half t7s  [T7R][SW];       //  8960 B fp16
    __shared__ __align__(16) __half stage[8][4][SPX];     //  6144 B per-wave

    // XCD swizzle: vertically-adjacent bands of one (img,strip) column land
    // on one XCD so the 30-row halo overlap reuses L2.
    const int id    = blockIdx.x;
    const int xcd   = id & 7;
    const int j8    = id >> 3;             // 0..255
    const int combo = j8 & 127;            // img*16 + strip
    const int sub   = j8 >> 7;             // 0..1
    const int band  = xcd * 2 + sub;       // 0..15
    const int img   = combo >> 4;
    const int strip = combo & 15;

    const int y0 = band * TH;
    const int x0 = strip * SW;
    const int t  = threadIdx.x;
    const int w    = t >> 6;               // wave 0..7
    const int lane = t & 63;

    const float* xb = x   + (size_t)img * 3 * HW;
    float*       ob = out + (size_t)img * 3 * HW;

    // ---- per-wave staging geometry: 4 rows x 24 units = 96 units over 64
    // lanes. unit0 = lane; unit1 = lane+64 (clamped duplicates -> branch-free) ----
    const int r0s = lane / UPR;                 // 0..2
    const int c0s = lane - UPR * r0s;
    const int u1  = lane + 64;                  // 64..127
    const int r1r = u1 / UPR;                   // 2..5
    const int r1s = r1r > 3 ? 3 : r1r;          // clamp -> duplicate slots
    const int c1s = u1 - UPR * r1r;             // 0..23
    const int col0 = x0 - SOFF + 4 * c0s;
    const int col1 = x0 - SOFF + 4 * c1s;
    const int col0c = col0 < 0 ? 0 : (col0 > WW - 4 ? WW - 4 : col0);
    const int col1c = col1 < 0 ? 0 : (col1 > WW - 4 ? WW - 4 : col1);
    const float cm0 = ((unsigned)col0 < (unsigned)WW) ? 1.f : 0.f;
    const float cm1 = ((unsigned)col1 < (unsigned)WW) ? 1.f : 0.f;

    float4 R0, G0, B0, R1, G1, B1;
    float  mk0, mk1;

    // issue iteration `it`'s global loads into registers — UNCONDITIONAL
    // (clamped addresses), masks applied at consume time.
    auto issue = [&](int it) {
        const int gbase = it * 32;
        {
            const int tr = gbase + 4 * w + r0s;
            const int y  = y0 - 15 + tr;
            const int yc = y < 0 ? 0 : (y > HH - 1 ? HH - 1 : y);
            mk0 = (tr < T31R && (unsigned)y < (unsigned)HH) ? cm0 : 0.f;
            const float* xr = xb + (size_t)yc * WW + col0c;
            R0 = *(const float4*)(xr);
            G0 = *(const float4*)(xr + HW);
            B0 = *(const float4*)(xr + 2 * HW);
        }
        {
            const int tr = gbase + 4 * w + r1s;
            const int y  = y0 - 15 + tr;
            const int yc = y < 0 ? 0 : (y > HH - 1 ? HH - 1 : y);
            mk1 = (tr < T31R && (unsigned)y < (unsigned)HH) ? cm1 : 0.f;
            const float* xr = xb + (size_t)yc * WW + col1c;
            R1 = *(const float4*)(xr);
            G1 = *(const float4*)(xr + HW);
            B1 = *(const float4*)(xr + 2 * HW);
        }
    };

    issue(0);   // prologue
    __builtin_amdgcn_sched_barrier(0);

    // -------- phase 1: barrier-free; wave w stages and h-blurs its own
    // rows tr = 32*it + 4w + r. --------
    for (int it = 0; it < NIT; ++it) {
        // consume prefetched regs -> masked fp16 luma into stage
        {
            union { float2 f; __half2 h[2]; } W;
            W.h[0] = __floats2half2_rn(mk0 * fmaf(0.2126f, R0.x, fmaf(0.7152f, G0.x, 0.0722f * B0.x)),
                                       mk0 * fmaf(0.2126f, R0.y, fmaf(0.7152f, G0.y, 0.0722f * B0.y)));
            W.h[1] = __floats2half2_rn(mk0 * fmaf(0.2126f, R0.z, fmaf(0.7152f, G0.z, 0.0722f * B0.z)),
                                       mk0 * fmaf(0.2126f, R0.w, fmaf(0.7152f, G0.w, 0.0722f * B0.w)));
            *(float2*)&stage[w][r0s][4 * c0s] = W.f;   // 8-byte aligned
            union { float2 f; __half2 h[2]; } V;
            V.h[0] = __floats2half2_rn(mk1 * fmaf(0.2126f, R1.x, fmaf(0.7152f, G1.x, 0.0722f * B1.x)),
                                       mk1 * fmaf(0.2126f, R1.y, fmaf(0.7152f, G1.y, 0.0722f * B1.y)));
            V.h[1] = __floats2half2_rn(mk1 * fmaf(0.2126f, R1.z, fmaf(0.7152f, G1.z, 0.0722f * B1.z)),
                                       mk1 * fmaf(0.2126f, R1.w, fmaf(0.7152f, G1.w, 0.0722f * B1.w)));
            *(float2*)&stage[w][r1s][4 * c1s] = V.f;
        }

        // issue next iteration's loads and FENCE: the scheduler cannot sink
        // them past this point, so the h-blur below covers their latency.
        if (it + 1 < NIT) {
            issue(it + 1);
        }
        __builtin_amdgcn_sched_barrier(0);

        // h-blur: thread -> stage row (t>>4)&3 of its own wave, 4 px at 4*(t&15)
        {
            const int lr = (t >> 4) & 3;
            const int c  = t & 15;
            const int tr = it * 32 + 4 * w + lr;
            if (tr < T31R) {
                float win[36];
                #pragma unroll
                for (int q = 0; q < 9; ++q) {
                    union { float2 f; __half2 h[2]; } U;
                    // win[i] <-> stage col 4c+i <-> image col x0-16+4c+i
                    U.f = *(const float2*)&stage[w][lr][4 * c + 4 * q];  // 8B aligned
                    const float2 a = __half22float2(U.h[0]);
                    const float2 b = __half22float2(U.h[1]);
                    win[4 * q]     = a.x; win[4 * q + 1] = a.y;
                    win[4 * q + 2] = b.x; win[4 * q + 3] = b.y;
                }
                float o[4] = {0.f, 0.f, 0.f, 0.f};
                float p[4] = {0.f, 0.f, 0.f, 0.f};
                #pragma unroll
                for (int s = 0; s < 31; ++s) {
                    const float g = GWC.g31[s];
                    o[0] = fmaf(g, win[1 + s], o[0]);
                    o[1] = fmaf(g, win[2 + s], o[1]);
                    o[2] = fmaf(g, win[3 + s], o[2]);
                    o[3] = fmaf(g, win[4 + s], o[3]);
                }
                #pragma unroll
                for (int s = 0; s < 7; ++s) {
                    const float g = GWC.g7[s];
                    p[0] = fmaf(g, win[13 + s], p[0]);
                    p[1] = fmaf(g, win[14 + s], p[1]);
                    p[2] = fmaf(g, win[15 + s], p[2]);
                    p[3] = fmaf(g, win[16 + s], p[3]);
                }
                // fp32 tile write: one b128
                *(float4*)&t31s[tr][4 * c] = make_float4(o[0], o[1], o[2], o[3]);
                if (tr >= 12 && tr < 12 + T7R) {
                    union { float2 f; __half2 h[2]; } V;
                    V.h[0] = __floats2half2_rn(p[0], p[1]);
                    V.h[1] = __floats2half2_rn(p[2], p[3]);
                    *(float2*)&t7s[tr - 12][4 * c] = V.f;
                }
            }
        }
        // NO __syncthreads here
    }

    __syncthreads();   // the ONLY barrier: t31s/t7s complete before phase 2

    // -------- phase 2: 4 cols x 2 rows/thread; each tap row read ONCE and
    // shared between the 2 rows (A0 gets g31[q], A1 gets g31[q-1]). --------
    const float ca = tanhf(clar[0]) * 0.5f;
    const float ta = tanhf(tex[0]) * 0.3f;

    const int rg = t >> 4;            // row group 0..31
    const int r0 = rg * 2;            // output rows r0, r0+1 (tile-rel)
    const int cc = 4 * (t & 15);      // col within tile, float4-aligned

    // issue x re-reads for BOTH rows now; conv below covers their latency
    const float* px0 = xb + (size_t)(y0 + r0) * WW + x0 + cc;
    const float* px1 = px0 + WW;
    const float4 Ra = *(const float4*)(px0);
    const float4 Ga = *(const float4*)(px0 + HW);
    const float4 Ba = *(const float4*)(px0 + 2 * HW);
    const float4 Rb = *(const float4*)(px1);
    const float4 Gb = *(const float4*)(px1 + HW);
    const float4 Bb = *(const float4*)(px1 + 2 * HW);
    __builtin_amdgcn_sched_barrier(0);

    float4 A0 = make_float4(0.f, 0.f, 0.f, 0.f);
    float4 A1 = make_float4(0.f, 0.f, 0.f, 0.f);
    #pragma unroll
    for (int q = 0; q < 32; ++q) {
        const float4 tap = *(const float4*)&t31s[r0 + q][cc];   // ds_read_b128
        if (q <= 30) {
            const float g = GWC.g31[q];
            A0.x = fmaf(g, tap.x, A0.x);
            A0.y = fmaf(g, tap.y, A0.y);
            A0.z = fmaf(g, tap.z, A0.z);
            A0.w = fmaf(g, tap.w, A0.w);
        }
        if (q >= 1) {
            const float g = GWC.g31[q - 1];
            A1.x = fmaf(g, tap.x, A1.x);
            A1.y = fmaf(g, tap.y, A1.y);
            A1.z = fmaf(g, tap.z, A1.z);
            A1.w = fmaf(g, tap.w, A1.w);
        }
    }
    float4 S0 = make_float4(0.f, 0.f, 0.f, 0.f);
    float4 S1 = make_float4(0.f, 0.f, 0.f, 0.f);
    #pragma unroll
    for (int q = 0; q < 8; ++q) {
        union { float2 f; __half2 h[2]; } U;
        U.f = *(const float2*)&t7s[r0 + q][cc];                 // ds_read_b64
        const float2 a = __half22float2(U.h[0]);
        const float2 b = __half22float2(U.h[1]);
        if (q <= 6) {
            const float g = GWC.g7[q];
            S0.x = fmaf(g, a.x, S0.x);
            S0.y = fmaf(g, a.y, S0.y);
            S0.z = fmaf(g, b.x, S0.z);
            S0.w = fmaf(g, b.y, S0.w);
        }
        if (q >= 1) {
            const float g = GWC.g7[q - 1];
            S1.x = fmaf(g, a.x, S1.x);
            S1.y = fmaf(g, a.y, S1.y);
            S1.z = fmaf(g, b.x, S1.z);
            S1.w = fmaf(g, b.y, S1.w);
        }
    }

    // combine + store both rows
    #pragma unroll
    for (int j = 0; j < 2; ++j) {
        const float4 R  = j ? Rb : Ra;
        const float4 G  = j ? Gb : Ga;
        const float4 Bc = j ? Bb : Ba;
        const float4 a31 = j ? A1 : A0;
        const float4 a7  = j ? S1 : S0;

        const float L0 = fmaf(0.2126f, R.x, fmaf(0.7152f, G.x, 0.0722f * Bc.x));
        const float L1 = fmaf(0.2126f, R.y, fmaf(0.7152f, G.y, 0.0722f * Bc.y));
        const float L2 = fmaf(0.2126f, R.z, fmaf(0.7152f, G.z, 0.0722f * Bc.z));
        const float L3 = fmaf(0.2126f, R.w, fmaf(0.7152f, G.w, 0.0722f * Bc.w));
        const float e0 = L0 + ca * (L0 - a31.x) + ta * (L0 - a7.x);
        const float e1 = L1 + ca * (L1 - a31.y) + ta * (L1 - a7.y);
        const float e2 = L2 + ca * (L2 - a31.z) + ta * (L2 - a7.z);
        const float e3 = L3 + ca * (L3 - a31.w) + ta * (L3 - a7.w);
        // v_rcp_f32 approx: rel err ~1ulp, far below the 3.9e-3 tolerance
        const float r0r = (e0 + 1e-6f) * __builtin_amdgcn_rcpf(L0 + 1e-6f);
        const float r1r = (e1 + 1e-6f) * __builtin_amdgcn_rcpf(L1 + 1e-6f);
        const float r2r = (e2 + 1e-6f) * __builtin_amdgcn_rcpf(L2 + 1e-6f);
        const float r3r = (e3 + 1e-6f) * __builtin_amdgcn_rcpf(L3 + 1e-6f);

        float4 o0, o1, o2;
        o0.x = fminf(fmaxf(R.x  * r0r, 0.f), 1.f);
        o0.y = fminf(fmaxf(R.y  * r1r, 0.f), 1.f);
        o0.z = fminf(fmaxf(R.z  * r2r, 0.f), 1.f);
        o0.w = fminf(fmaxf(R.w  * r3r, 0.f), 1.f);
        o1.x = fminf(fmaxf(G.x  * r0r, 0.f), 1.f);
        o1.y = fminf(fmaxf(G.y  * r1r, 0.f), 1.f);
        o1.z = fminf(fmaxf(G.z  * r2r, 0.f), 1.f);
        o1.w = fminf(fmaxf(G.w  * r3r, 0.f), 1.f);
        o2.x = fminf(fmaxf(Bc.x * r0r, 0.f), 1.f);
        o2.y = fminf(fmaxf(Bc.y * r1r, 0.f), 1.f);
        o2.z = fminf(fmaxf(Bc.z * r2r, 0.f), 1.f);
        o2.w = fminf(fmaxf(Bc.w * r3r, 0.f), 1.f);

        float* qo = ob + (size_t)(y0 + r0 + j) * WW + x0 + cc;
        *(float4*)(qo)          = o0;
        *(float4*)(qo + HW)     = o1;
        *(float4*)(qo + 2 * HW) = o2;
    }
}

extern "C" void kernel_launch(void* const* d_in, const int* in_sizes, int n_in,
                              void* d_out, int out_size, void* d_ws, size_t ws_size,
                              hipStream_t stream) {
    const float* x    = (const float*)d_in[0];
    const float* clar = (const float*)d_in[1];
    const float* tex  = (const float*)d_in[2];
    float* out = (float*)d_out;

    dim3 grid(8 * 16 * 16);  // 2048 blocks: 8 imgs x 16 strips x 16 bands; 4/CU x 2 rounds
    dim3 block(512);
    hipLaunchKernelGGL(fused_tile, grid, block, 0, stream, x, clar, tex, out);
}